// Round 1
// baseline (213.053 us; speedup 1.0000x reference)
//
#include <hip/hip_runtime.h>
#include <hip/hip_bf16.h>
#include <cstdint>

typedef __bf16 bf16_t;
typedef bf16_t bf16x8 __attribute__((ext_vector_type(8)));
typedef float  f32x4  __attribute__((ext_vector_type(4)));

#define S0 512
#define S1 256
#define S2 128
#define NGRID 128
#define GPTS (NGRID*NGRID)   // 16384
#define TG 64                // grid rows per workgroup

// workspace layout (bytes)
#define WS_BASE 0u
#define WS_W1P  32768u                          // 16*16*16*64*8 bf16 = 4 MB
#define WS_W2P  (32768u + 4194304u)             // 1 MB
#define WS_W3P  (32768u + 4194304u + 1048576u)  // 64 KB

// ---------------------------------------------------------------------------
// P1: base[m][o] = W0a[m,o,:]·x0 + b0a[m,o] + b0b[m,o]   (fp32, one wave/out)
// ---------------------------------------------------------------------------
__global__ __launch_bounds__(256) void prep_base_k(
    const float* __restrict__ x0, const float* __restrict__ W0a,
    const float* __restrict__ b0a, const float* __restrict__ b0b,
    float* __restrict__ base)
{
  int wid = (blockIdx.x << 2) + (threadIdx.x >> 6);   // 0..8191
  int L = threadIdx.x & 63;
  int m = wid >> 9, o = wid & 511;
  const float* wrow = W0a + ((size_t)(m*S0 + o) << 10);
  float acc = 0.f;
#pragma unroll
  for (int i = 0; i < 4; ++i) {
    f32x4 wv = *(const f32x4*)(wrow + i*256 + L*4);
    f32x4 xv = *(const f32x4*)(x0   + i*256 + L*4);
    acc += wv.x*xv.x + wv.y*xv.y + wv.z*xv.z + wv.w*xv.w;
  }
#pragma unroll
  for (int s = 32; s; s >>= 1) acc += __shfl_xor(acc, s, 64);
  if (L == 0) base[m*S0 + o] = acc + b0a[m*S0 + o] + b0b[m*S0 + o];
}

// ---------------------------------------------------------------------------
// P2: pack W1/W2/W3 (fp32, row-major [m][n][k]) into bf16 MFMA-B-fragment
// order: [m][ks][nt][lane][8], lane holds B[k=ks*32+(L>>4)*8+j][n=nt*16+(L&15)]
// (j-contiguous in k == contiguous in source row). W3 padded N 3->16 w/ zeros.
// ---------------------------------------------------------------------------
__global__ __launch_bounds__(256) void prep_pack_k(
    const float* __restrict__ W1, const float* __restrict__ W2,
    const float* __restrict__ W3, bf16_t* __restrict__ W1p,
    bf16_t* __restrict__ W2p, bf16_t* __restrict__ W3p)
{
  int T = blockIdx.x * 256 + threadIdx.x;  // 331776 total
  const float* src = nullptr;
  bf16_t* dst = nullptr;
  if (T < 262144) {                 // W1: 16m * 16ks * 16nt * 64L
    int L = T & 63, nt = (T >> 6) & 15, ks = (T >> 10) & 15, m = T >> 14;
    int n = nt*16 + (L & 15), k0 = ks*32 + ((L >> 4) & 3)*8;
    src = W1 + (size_t)(m*S1 + n)*S0 + k0;
    dst = W1p + (size_t)T*8;
  } else if (T < 262144 + 65536) {  // W2: 16m * 8ks * 8nt * 64L
    int T2 = T - 262144;
    int L = T2 & 63, nt = (T2 >> 6) & 7, ks = (T2 >> 9) & 7, m = T2 >> 12;
    int n = nt*16 + (L & 15), k0 = ks*32 + ((L >> 4) & 3)*8;
    src = W2 + (size_t)(m*S2 + n)*S1 + k0;
    dst = W2p + (size_t)T2*8;
  } else {                          // W3: 16m * 4ks * 1nt * 64L (N padded to 16)
    int T3 = T - 327680;
    int L = T3 & 63, ks = (T3 >> 6) & 3, m = T3 >> 8;
    int n = L & 15, k0 = ks*32 + ((L >> 4) & 3)*8;
    dst = W3p + (size_t)T3*8;
    if (n < 3) src = W3 + (size_t)(m*3 + n)*S2 + k0;
  }
  bf16x8 v;
  if (src) {
    f32x4 a = *(const f32x4*)src;
    f32x4 b = *(const f32x4*)(src + 4);
    v[0]=(bf16_t)a.x; v[1]=(bf16_t)a.y; v[2]=(bf16_t)a.z; v[3]=(bf16_t)a.w;
    v[4]=(bf16_t)b.x; v[5]=(bf16_t)b.y; v[6]=(bf16_t)b.z; v[7]=(bf16_t)b.w;
  } else {
#pragma unroll
    for (int j = 0; j < 8; ++j) v[j] = (bf16_t)0.f;
  }
  *(bf16x8*)dst = v;
}

// ---------------------------------------------------------------------------
// Main fused kernel: one WG = one (m, 64-row grid tile). 4 waves.
//  L1: [64x512]@[512x256]  L2: [64x256]@[256x128]  L3: [64x128]@[128x16(3)]
// A via LDS (layer-0 recomputed per 32-K chunk, packed frag order, dbuf);
// B frags direct from L2 (packed). C/D: col=lane&15, row=(lane>>4)*4+reg.
// A: row=lane&15, k=(lane>>4)*8+j.  B: col=lane&15, k=(lane>>4)*8+j.
// ---------------------------------------------------------------------------
__global__ __launch_bounds__(256, 2) void fused_mlp_k(
    const float* __restrict__ base, const float* __restrict__ W0b,
    const bf16_t* __restrict__ W1p, const bf16_t* __restrict__ W2p,
    const bf16_t* __restrict__ W3p,
    const float* __restrict__ b1, const float* __restrict__ b2,
    const float* __restrict__ b3, float* __restrict__ out)
{
  __shared__ bf16_t sA1[TG*264];     // L1 out bf16 [64][256] stride 264 (33792 B); reused as h2 [64][128] stride 136
  __shared__ bf16_t sA0[2][2048];    // packed A0 chunk frags [4 mt][64 lane][8], dbuf (8192 B)

  const int bid  = blockIdx.x;                       // 4096
  const int m    = ((bid & 7) << 1) | (bid >> 11);   // 2 MLPs per XCD -> L2-resident weights
  const int tile = (bid >> 3) & 255;
  const int g0   = tile * TG;

  const int tid  = threadIdx.x;
  const int w    = tid >> 6, L = tid & 63;
  const int quad = L >> 4, lrow = L & 15;

  const float step = 2.0f / 127.0f;
  const float yv = -1.0f + (float)(tile >> 1) * step;        // whole tile shares one y
  const int   rc = (w << 4) | lrow;                          // row this thread generates h0 for
  const float xv = -1.0f + (float)(((tile & 1) << 6) + rc) * step;

  const float* basep = base + m*S0;
  const float* w0bp  = W0b + (size_t)m*S0*2;

  f32x4 zero = {0.f, 0.f, 0.f, 0.f};
  f32x4 acc1[4][4];
#pragma unroll
  for (int a = 0; a < 4; ++a)
#pragma unroll
    for (int b = 0; b < 4; ++b) acc1[a][b] = zero;

  // ---------------- Layer 1: K=512, 16 chunks of 32 ----------------
  for (int ks = 0; ks < 16; ++ks) {
    // generate 8 h0 values (row rc, k = kk..kk+7), fp32 math then bf16
    int kk = ks*32 + quad*8;
    f32x4 cA = *(const f32x4*)(basep + kk);
    f32x4 cB = *(const f32x4*)(basep + kk + 4);
    f32x4 w0 = *(const f32x4*)(w0bp + kk*2);
    f32x4 w1v = *(const f32x4*)(w0bp + kk*2 + 4);
    f32x4 w2v = *(const f32x4*)(w0bp + kk*2 + 8);
    f32x4 w3v = *(const f32x4*)(w0bp + kk*2 + 12);
    float c[8]  = {cA.x, cA.y, cA.z, cA.w, cB.x, cB.y, cB.z, cB.w};
    float wx[8] = {w0.x, w0.z, w1v.x, w1v.z, w2v.x, w2v.z, w3v.x, w3v.z};
    float wy[8] = {w0.y, w0.w, w1v.y, w1v.w, w2v.y, w2v.w, w3v.y, w3v.w};
    bf16x8 hv;
#pragma unroll
    for (int j = 0; j < 8; ++j)
      hv[j] = (bf16_t)fmaxf(fmaf(wx[j], xv, fmaf(wy[j], yv, c[j])), 0.f);
    *(bf16x8*)(&sA0[ks & 1][tid * 8]) = hv;   // slot (mt=w, lane=L)
    __syncthreads();

    bf16x8 af[4];
#pragma unroll
    for (int mt = 0; mt < 4; ++mt)
      af[mt] = *(const bf16x8*)(&sA0[ks & 1][(mt*64 + L)*8]);

    const bf16_t* bp = W1p + (((size_t)(m*16 + ks)*16 + w*4)*64 + L)*8;
#pragma unroll
    for (int n = 0; n < 4; ++n) {
      bf16x8 bfr = *(const bf16x8*)(bp + (size_t)n*512);
#pragma unroll
      for (int mt = 0; mt < 4; ++mt)
        acc1[mt][n] = __builtin_amdgcn_mfma_f32_16x16x32_bf16(af[mt], bfr, acc1[mt][n], 0, 0, 0);
    }
  }

  // L1 epilogue: +b1, relu, bf16 -> sA1 row-major [64][256] stride 264
#pragma unroll
  for (int n = 0; n < 4; ++n) {
    int col = (w*4 + n)*16 + lrow;
    float bb = b1[m*S1 + col];
#pragma unroll
    for (int mt = 0; mt < 4; ++mt)
#pragma unroll
      for (int p = 0; p < 4; ++p) {
        int row = mt*16 + quad*4 + p;
        sA1[row*264 + col] = (bf16_t)fmaxf(acc1[mt][n][p] + bb, 0.f);
      }
  }
  __syncthreads();

  // ---------------- Layer 2: K=256, 8 chunks ----------------
  f32x4 acc2[4][2];
#pragma unroll
  for (int a = 0; a < 4; ++a) { acc2[a][0] = zero; acc2[a][1] = zero; }
  for (int ks = 0; ks < 8; ++ks) {
    int k2 = ks*32 + quad*8;
    bf16x8 af[4];
#pragma unroll
    for (int mt = 0; mt < 4; ++mt)
      af[mt] = *(const bf16x8*)(&sA1[(mt*16 + lrow)*264 + k2]);
    const bf16_t* bp = W2p + (((size_t)(m*8 + ks)*8 + w*2)*64 + L)*8;
#pragma unroll
    for (int n = 0; n < 2; ++n) {
      bf16x8 bfr = *(const bf16x8*)(bp + (size_t)n*512);
#pragma unroll
      for (int mt = 0; mt < 4; ++mt)
        acc2[mt][n] = __builtin_amdgcn_mfma_f32_16x16x32_bf16(af[mt], bfr, acc2[mt][n], 0, 0, 0);
    }
  }
  __syncthreads();   // everyone done reading sA1 before overwrite as h2

  // L2 epilogue: +b2, relu, bf16 -> h2 [64][128] stride 136 (aliases sA1)
  bf16_t* sH2 = sA1;
#pragma unroll
  for (int n = 0; n < 2; ++n) {
    int col = (w*2 + n)*16 + lrow;
    float bb = b2[m*S2 + col];
#pragma unroll
    for (int mt = 0; mt < 4; ++mt)
#pragma unroll
      for (int p = 0; p < 4; ++p) {
        int row = mt*16 + quad*4 + p;
        sH2[row*136 + col] = (bf16_t)fmaxf(acc2[mt][n][p] + bb, 0.f);
      }
  }
  __syncthreads();

  // ---------------- Layer 3: K=128, N padded to 16; wave w does rows [16w,16w+16) ----------------
  f32x4 acc3 = zero;
#pragma unroll
  for (int ks = 0; ks < 4; ++ks) {
    bf16x8 af = *(const bf16x8*)(&sH2[(w*16 + lrow)*136 + ks*32 + quad*8]);
    bf16x8 bfr = *(const bf16x8*)(W3p + (((size_t)m*4 + ks)*64 + L)*8);
    acc3 = __builtin_amdgcn_mfma_f32_16x16x32_bf16(af, bfr, acc3, 0, 0, 0);
  }
  if (lrow < 3) {
    float bb = b3[m*3 + lrow];
#pragma unroll
    for (int p = 0; p < 4; ++p) {
      int row = w*16 + quad*4 + p;
      out[((size_t)m*GPTS + g0 + row)*3 + lrow] = tanhf(acc3[p] + bb);
    }
  }
}

// ---------------------------------------------------------------------------
extern "C" void kernel_launch(void* const* d_in, const int* in_sizes, int n_in,
                              void* d_out, int out_size, void* d_ws, size_t ws_size,
                              hipStream_t stream) {
  const float* x0  = (const float*)d_in[0];
  const float* W0a = (const float*)d_in[1];
  const float* b0a = (const float*)d_in[2];
  const float* W0b = (const float*)d_in[3];
  const float* b0b = (const float*)d_in[4];
  const float* W1  = (const float*)d_in[5];
  const float* b1  = (const float*)d_in[6];
  const float* W2  = (const float*)d_in[7];
  const float* b2  = (const float*)d_in[8];
  const float* W3  = (const float*)d_in[9];
  const float* b3  = (const float*)d_in[10];
  // d_in[11] = n_grid_step == 128 (fixed by setup_inputs; grid dims must be host-known)

  char* ws = (char*)d_ws;
  float*  base = (float*)(ws + WS_BASE);
  bf16_t* W1p  = (bf16_t*)(ws + WS_W1P);
  bf16_t* W2p  = (bf16_t*)(ws + WS_W2P);
  bf16_t* W3p  = (bf16_t*)(ws + WS_W3P);
  float*  out  = (float*)d_out;

  prep_base_k<<<2048, 256, 0, stream>>>(x0, W0a, b0a, b0b, base);
  prep_pack_k<<<1296, 256, 0, stream>>>(W1, W2, W3, W1p, W2p, W3p);
  fused_mlp_k<<<4096, 256, 0, stream>>>(base, W0b, W1p, W2p, W3p, b1, b2, b3, out);
}

// Round 2
// 206.812 us; speedup vs baseline: 1.0302x; 1.0302x over previous
//
#include <hip/hip_runtime.h>
#include <hip/hip_bf16.h>
#include <cstdint>

typedef __bf16 bf16_t;
typedef bf16_t bf16x8 __attribute__((ext_vector_type(8)));
typedef bf16_t bf16x4 __attribute__((ext_vector_type(4)));
typedef float  f32x4  __attribute__((ext_vector_type(4)));

#define S0 512
#define S1 256
#define S2 128
#define NGRID 128
#define GPTS (NGRID*NGRID)   // 16384

// workspace layout (bytes)
#define WS_BASE 0u
#define WS_W1P  32768u                          // 16*16*16*64*8 bf16 = 4 MB
#define WS_W2P  (32768u + 4194304u)             // 1 MB
#define WS_W3P  (32768u + 4194304u + 1048576u)  // 64 KB

__device__ __forceinline__ float tanh_fast(float x) {
  // tanh(x) = 1 - 2/(e^{2x}+1); exp2-based, saturates correctly at +/-inf
  float e = __builtin_amdgcn_exp2f(x * 2.88539008f);   // 2*log2(e)
  return fmaf(-2.0f, __builtin_amdgcn_rcpf(e + 1.0f), 1.0f);
}

// ---------------------------------------------------------------------------
// Merged prep: blocks [0,2048): base[m][o] = W0a·x0 + b0a + b0b  (fp32)
//              blocks [2048,3344): pack W1/W2/W3 into bf16 MFMA B-frag order
//              [m][ks][nt][lane][8]: lane holds W[k=ks*32+(L>>4)*8+j][n=nt*16+(L&15)]
// ---------------------------------------------------------------------------
__global__ __launch_bounds__(256) void prep_k(
    const float* __restrict__ x0, const float* __restrict__ W0a,
    const float* __restrict__ b0a, const float* __restrict__ b0b,
    const float* __restrict__ W1, const float* __restrict__ W2,
    const float* __restrict__ W3, float* __restrict__ base,
    bf16_t* __restrict__ W1p, bf16_t* __restrict__ W2p, bf16_t* __restrict__ W3p)
{
  if (blockIdx.x < 2048) {
    int wid = (blockIdx.x << 2) + (threadIdx.x >> 6);   // 0..8191
    int L = threadIdx.x & 63;
    int m = wid >> 9, o = wid & 511;
    const float* wrow = W0a + ((size_t)(m*S0 + o) << 10);
    float acc = 0.f;
#pragma unroll
    for (int i = 0; i < 4; ++i) {
      f32x4 wv = *(const f32x4*)(wrow + i*256 + L*4);
      f32x4 xv = *(const f32x4*)(x0   + i*256 + L*4);
      acc += wv.x*xv.x + wv.y*xv.y + wv.z*xv.z + wv.w*xv.w;
    }
#pragma unroll
    for (int s = 32; s; s >>= 1) acc += __shfl_xor(acc, s, 64);
    if (L == 0) base[m*S0 + o] = acc + b0a[m*S0 + o] + b0b[m*S0 + o];
    return;
  }

  int T = (blockIdx.x - 2048) * 256 + threadIdx.x;  // 331776 total
  const float* src = nullptr;
  bf16_t* dst = nullptr;
  if (T < 262144) {                 // W1: 16m * 16ks * 16nt * 64L
    int L = T & 63, nt = (T >> 6) & 15, ks = (T >> 10) & 15, m = T >> 14;
    int n = nt*16 + (L & 15), k0 = ks*32 + ((L >> 4) & 3)*8;
    src = W1 + (size_t)(m*S1 + n)*S0 + k0;
    dst = W1p + (size_t)T*8;
  } else if (T < 262144 + 65536) {  // W2: 16m * 8ks * 8nt * 64L
    int T2 = T - 262144;
    int L = T2 & 63, nt = (T2 >> 6) & 7, ks = (T2 >> 9) & 7, m = T2 >> 12;
    int n = nt*16 + (L & 15), k0 = ks*32 + ((L >> 4) & 3)*8;
    src = W2 + (size_t)(m*S2 + n)*S1 + k0;
    dst = W2p + (size_t)T2*8;
  } else {                          // W3: 16m * 4ks * 1nt * 64L (N padded to 16)
    int T3 = T - 327680;
    int L = T3 & 63, ks = (T3 >> 6) & 3, m = T3 >> 8;
    int n = L & 15, k0 = ks*32 + ((L >> 4) & 3)*8;
    dst = W3p + (size_t)T3*8;
    if (n < 3) src = W3 + (size_t)(m*3 + n)*S2 + k0;
  }
  bf16x8 v;
  if (src) {
    f32x4 a = *(const f32x4*)src;
    f32x4 b = *(const f32x4*)(src + 4);
    v[0]=(bf16_t)a.x; v[1]=(bf16_t)a.y; v[2]=(bf16_t)a.z; v[3]=(bf16_t)a.w;
    v[4]=(bf16_t)b.x; v[5]=(bf16_t)b.y; v[6]=(bf16_t)b.z; v[7]=(bf16_t)b.w;
  } else {
#pragma unroll
    for (int j = 0; j < 8; ++j) v[j] = (bf16_t)0.f;
  }
  *(bf16x8*)dst = v;
}

// ---------------------------------------------------------------------------
// Fused MLP. One WG = (m = bid>>8, 64-row grid tile = bid&255); m-major so all
// concurrent WGs share 2-3 m's -> packed weights L2-resident per XCD.
// L1 K-loop: barrier-free; each wave redundantly generates its own A-frags in
// registers (VALU, 4-wide pipe) instead of LDS round-trip (1-wide pipe).
// MFMA operands swapped (B,A) -> D = C^T: thread holds 4 column-contiguous
// outputs -> packed b64 LDS stores. Frag layouts (A and B identical):
//   row/col = lane&15, k = (lane>>4)*8+j;  C/D: col = lane&15, row = quad*4+p.
// ---------------------------------------------------------------------------
__global__ __launch_bounds__(256, 3) void fused_mlp_k(
    const float* __restrict__ base, const float* __restrict__ W0b,
    const bf16_t* __restrict__ W1p, const bf16_t* __restrict__ W2p,
    const bf16_t* __restrict__ W3p,
    const float* __restrict__ b1, const float* __restrict__ b2,
    const float* __restrict__ b3, float* __restrict__ out)
{
  __shared__ __align__(16) bf16_t sA1[64*264];  // 33792 B; reused as h2 [64][136]

  const int bid  = blockIdx.x;
  const int m    = bid >> 8;            // m-major: L2-resident weights
  const int tile = bid & 255;
  const int g0   = tile * 64;

  const int tid  = threadIdx.x;
  const int w    = tid >> 6, L = tid & 63;
  const int quad = L >> 4, lrow = L & 15;

  const float step = 2.0f / 127.0f;
  const float yv  = -1.0f + (float)(tile >> 1) * step;
  const float xv0 = -1.0f + (float)(((tile & 1) << 6) + lrow) * step;  // mt=0 row

  const float* basep = base + m*S0;
  const float* w0bp  = W0b + (size_t)m*S0*2;

  f32x4 zero = {0.f, 0.f, 0.f, 0.f};
  f32x4 acc1[4][4];
#pragma unroll
  for (int a = 0; a < 4; ++a)
#pragma unroll
    for (int b = 0; b < 4; ++b) acc1[a][b] = zero;

  // ---------------- Layer 1: K=512, 16 chunks, no barriers ----------------
  const bf16_t* bp1 = W1p + (((size_t)(m*16)*16 + w*4)*64 + L)*8;
  bf16x8 Bc[4];
#pragma unroll
  for (int n = 0; n < 4; ++n) Bc[n] = *(const bf16x8*)(bp1 + (size_t)n*512);

#pragma unroll 2
  for (int ks = 0; ks < 16; ++ks) {
    const int kk = ks*32 + quad*8;
    f32x4 cA  = *(const f32x4*)(basep + kk);
    f32x4 cB  = *(const f32x4*)(basep + kk + 4);
    f32x4 wv0 = *(const f32x4*)(w0bp + kk*2);
    f32x4 wv1 = *(const f32x4*)(w0bp + kk*2 + 4);
    f32x4 wv2 = *(const f32x4*)(w0bp + kk*2 + 8);
    f32x4 wv3 = *(const f32x4*)(w0bp + kk*2 + 12);

    bf16x8 Bn[4];
    if (ks < 15) {
#pragma unroll
      for (int n = 0; n < 4; ++n)
        Bn[n] = *(const bf16x8*)(bp1 + (size_t)(ks+1)*8192 + (size_t)n*512);
    }

    float t[8], wx[8];
    t[0] = fmaf(wv0.y, yv, cA.x); wx[0] = wv0.x;
    t[1] = fmaf(wv0.w, yv, cA.y); wx[1] = wv0.z;
    t[2] = fmaf(wv1.y, yv, cA.z); wx[2] = wv1.x;
    t[3] = fmaf(wv1.w, yv, cA.w); wx[3] = wv1.z;
    t[4] = fmaf(wv2.y, yv, cB.x); wx[4] = wv2.x;
    t[5] = fmaf(wv2.w, yv, cB.y); wx[5] = wv2.z;
    t[6] = fmaf(wv3.y, yv, cB.z); wx[6] = wv3.x;
    t[7] = fmaf(wv3.w, yv, cB.w); wx[7] = wv3.z;

#pragma unroll
    for (int mt = 0; mt < 4; ++mt) {
      const float xr = xv0 + (float)(mt*16)*step;
      bf16x8 af;
#pragma unroll
      for (int j = 0; j < 8; ++j)
        af[j] = (bf16_t)fmaxf(fmaf(wx[j], xr, t[j]), 0.f);
#pragma unroll
      for (int n = 0; n < 4; ++n)
        acc1[mt][n] = __builtin_amdgcn_mfma_f32_16x16x32_bf16(Bc[n], af, acc1[mt][n], 0, 0, 0);
    }
    if (ks < 15) {
#pragma unroll
      for (int n = 0; n < 4; ++n) Bc[n] = Bn[n];
    }
  }

  // L1 epilogue: D^T -> thread holds 4 contiguous cols -> packed b64 stores
#pragma unroll
  for (int nb = 0; nb < 4; ++nb) {
    const int col = w*64 + nb*16 + quad*4;
    f32x4 bb = *(const f32x4*)(b1 + m*S1 + col);
#pragma unroll
    for (int mt = 0; mt < 4; ++mt) {
      const int row = mt*16 + lrow;
      bf16x4 v;
#pragma unroll
      for (int p = 0; p < 4; ++p)
        v[p] = (bf16_t)fmaxf(acc1[mt][nb][p] + bb[p], 0.f);
      *(bf16x4*)(&sA1[row*264 + col]) = v;
    }
  }
  __syncthreads();

  // ---------------- Layer 2: K=256, 8 chunks, barrier-free loop ----------------
  f32x4 acc2[4][2];
#pragma unroll
  for (int a = 0; a < 4; ++a) { acc2[a][0] = zero; acc2[a][1] = zero; }
  const bf16_t* bp2 = W2p + (((size_t)(m*8)*8 + w*2)*64 + L)*8;
#pragma unroll 2
  for (int ks = 0; ks < 8; ++ks) {
    const int k2 = ks*32 + quad*8;
    bf16x8 af[4];
#pragma unroll
    for (int mt = 0; mt < 4; ++mt)
      af[mt] = *(const bf16x8*)(&sA1[(mt*16 + lrow)*264 + k2]);
    bf16x8 b0f = *(const bf16x8*)(bp2 + (size_t)ks*4096);
    bf16x8 b1f = *(const bf16x8*)(bp2 + (size_t)ks*4096 + 512);
#pragma unroll
    for (int mt = 0; mt < 4; ++mt)
      acc2[mt][0] = __builtin_amdgcn_mfma_f32_16x16x32_bf16(b0f, af[mt], acc2[mt][0], 0, 0, 0);
#pragma unroll
    for (int mt = 0; mt < 4; ++mt)
      acc2[mt][1] = __builtin_amdgcn_mfma_f32_16x16x32_bf16(b1f, af[mt], acc2[mt][1], 0, 0, 0);
  }
  __syncthreads();   // all sA1 reads done before aliased h2 writes

  // L2 epilogue: h2 -> sH2 [64][136], packed b64 stores
  bf16_t* sH2 = sA1;
#pragma unroll
  for (int nb = 0; nb < 2; ++nb) {
    const int col = w*32 + nb*16 + quad*4;
    f32x4 bb = *(const f32x4*)(b2 + m*S2 + col);
#pragma unroll
    for (int mt = 0; mt < 4; ++mt) {
      const int row = mt*16 + lrow;
      bf16x4 v;
#pragma unroll
      for (int p = 0; p < 4; ++p)
        v[p] = (bf16_t)fmaxf(acc2[mt][nb][p] + bb[p], 0.f);
      *(bf16x4*)(&sH2[row*136 + col]) = v;
    }
  }
  __syncthreads();

  // ---------------- Layer 3: K=128, N padded to 16 ----------------
  f32x4 acc3 = zero;
#pragma unroll
  for (int ks = 0; ks < 4; ++ks) {
    bf16x8 af  = *(const bf16x8*)(&sH2[(w*16 + lrow)*136 + ks*32 + quad*8]);
    bf16x8 bfr = *(const bf16x8*)(W3p + (((size_t)m*4 + ks)*64 + L)*8);
    acc3 = __builtin_amdgcn_mfma_f32_16x16x32_bf16(bfr, af, acc3, 0, 0, 0);
  }
  if (quad == 0) {   // thread holds channels p=0..3 for grid row w*16+lrow
    const size_t o = ((size_t)m*GPTS + g0 + w*16 + lrow)*3;
    out[o + 0] = tanh_fast(acc3[0] + b3[m*3 + 0]);
    out[o + 1] = tanh_fast(acc3[1] + b3[m*3 + 1]);
    out[o + 2] = tanh_fast(acc3[2] + b3[m*3 + 2]);
  }
}

// ---------------------------------------------------------------------------
extern "C" void kernel_launch(void* const* d_in, const int* in_sizes, int n_in,
                              void* d_out, int out_size, void* d_ws, size_t ws_size,
                              hipStream_t stream) {
  const float* x0  = (const float*)d_in[0];
  const float* W0a = (const float*)d_in[1];
  const float* b0a = (const float*)d_in[2];
  const float* W0b = (const float*)d_in[3];
  const float* b0b = (const float*)d_in[4];
  const float* W1  = (const float*)d_in[5];
  const float* b1  = (const float*)d_in[6];
  const float* W2  = (const float*)d_in[7];
  const float* b2  = (const float*)d_in[8];
  const float* W3  = (const float*)d_in[9];
  const float* b3  = (const float*)d_in[10];

  char* ws = (char*)d_ws;
  float*  base = (float*)(ws + WS_BASE);
  bf16_t* W1p  = (bf16_t*)(ws + WS_W1P);
  bf16_t* W2p  = (bf16_t*)(ws + WS_W2P);
  bf16_t* W3p  = (bf16_t*)(ws + WS_W3P);
  float*  out  = (float*)d_out;

  prep_k<<<3344, 256, 0, stream>>>(x0, W0a, b0a, b0b, W1, W2, W3, base, W1p, W2p, W3p);
  fused_mlp_k<<<4096, 256, 0, stream>>>(base, W0b, W1p, W2p, W3p, b1, b2, b3, out);
}